// Round 4
// baseline (472.385 us; speedup 1.0000x reference)
//
#include <hip/hip_runtime.h>

#define HWPIX 16384
#define XSTR 200   // lx stride in shorts (100 words); per-wave quarter also hosts lh
#define HSTR 104   // lh stride in shorts (52 words)
#define L2E 1.4426950408889634f

typedef float f32x4 __attribute__((ext_vector_type(4)));
typedef short s16x8 __attribute__((ext_vector_type(8)));

static __device__ __forceinline__ unsigned short f2bf(float f) {
    unsigned int u = __builtin_bit_cast(unsigned int, f);
    u += 0x7fffu + ((u >> 16) & 1u);
    return (unsigned short)(u >> 16);
}
static __device__ __forceinline__ unsigned int pack2(float lo, float hi) {
    return (unsigned int)f2bf(lo) | ((unsigned int)f2bf(hi) << 16);
}
// HW packed f32->bf16 (RNE), one instruction for two converts
static __device__ __forceinline__ unsigned int cvtpk(float lo, float hi) {
    unsigned int r;
    asm("v_cvt_pk_bf16_f32 %0, %1, %2" : "=v"(r) : "v"(lo), "v"(hi));
    return r;
}

#define SBAR() __builtin_amdgcn_sched_barrier(0)

// ws layout: floats [0,1536) gmean, [1536,3072) xg, [3072,3168) s1l, [3168,3264) t1l,
// [3264,3456) s2l, [3456,3648) t2l. Byte 16384: W1 bf16 frags (36864 B), then W2 frags.

__global__ __launch_bounds__(256) void prep_kernel(
    const float* __restrict__ x1, const float* __restrict__ x2, const float* __restrict__ x3,
    const float* __restrict__ lw1, const float* __restrict__ lb1,
    const float* __restrict__ lg1, const float* __restrict__ lbe1,
    const float* __restrict__ lm1, const float* __restrict__ lv1,
    const float* __restrict__ lw2, const float* __restrict__ lb2,
    const float* __restrict__ lg2, const float* __restrict__ lbe2,
    const float* __restrict__ lm2, const float* __restrict__ lv2,
    float* __restrict__ wsf, unsigned short* __restrict__ w1f, unsigned short* __restrict__ w2f)
{
    const int bid = blockIdx.x, t = threadIdx.x;
    if (bid < 1536) {
        // GAP over one (b, channel) fp32 plane: 16384 floats
        int b = bid / 192, c = bid % 192;
        int g = c >> 6, cc = c & 63;
        const float* base = (g == 0 ? x1 : (g == 1 ? x2 : x3)) + ((size_t)(b * 64 + cc)) * HWPIX;
        float s = 0.f;
        #pragma unroll
        for (int it = 0; it < 16; ++it) {
            f32x4 v = *(const f32x4*)(base + it * 1024 + t * 4);
            s += v[0] + v[1] + v[2] + v[3];
        }
        for (int off = 32; off > 0; off >>= 1) s += __shfl_down(s, off, 64);
        __shared__ float part[4];
        if ((t & 63) == 0) part[t >> 6] = s;
        __syncthreads();
        if (t == 0) wsf[bid] = (part[0] + part[1] + part[2] + part[3]) * (1.f / (float)HWPIX);
    } else if (bid == 1536) {
        if (t < 96) {
            float s = lg1[t] * __frsqrt_rn(lv1[t] + 1e-5f);
            wsf[3072 + t] = s;
            wsf[3168 + t] = (lb1[t] - lm1[t]) * s + lbe1[t];
        }
    } else if (bid == 1537) {
        if (t < 192) {
            float s = lg2[t] * __frsqrt_rn(lv2[t] + 1e-5f);
            wsf[3264 + t] = s;
            wsf[3456 + t] = (lb2[t] - lm2[t]) * s + lbe2[t];
        }
    } else if (bid < 1547) {
        // W1 pretile fp32 -> bf16 B-frags. frag f = kb*6+nb; lane l holds
        // B[k=(l>>4)*8+j][n=l&15] with B=W1^T -> W1[row=n][col=k..k+7]
        int slot = (bid - 1538) * 256 + t;          // [0, 2304)
        int f = slot >> 6, l = slot & 63;
        int kb = f / 6, nb = f % 6;
        int row = nb * 16 + (l & 15), col0 = kb * 32 + ((l >> 4) << 3);
        const float* src = lw1 + row * 192 + col0;
        f32x4 a = *(const f32x4*)src, b4 = *(const f32x4*)(src + 4);
        unsigned int* dst = (unsigned int*)(w1f + f * 512 + l * 8);
        dst[0] = pack2(a[0], a[1]); dst[1] = pack2(a[2], a[3]);
        dst[2] = pack2(b4[0], b4[1]); dst[3] = pack2(b4[2], b4[3]);
    } else {
        // W2 pretile: frag f = kb*12+nb; W2[row=n][col=k..k+7], rows 0..191, cols 0..95
        int slot = (bid - 1547) * 256 + t;
        int f = slot >> 6, l = slot & 63;
        int kb = f / 12, nb = f % 12;
        int row = nb * 16 + (l & 15), col0 = kb * 32 + ((l >> 4) << 3);
        const float* src = lw2 + row * 96 + col0;
        f32x4 a = *(const f32x4*)src, b4 = *(const f32x4*)(src + 4);
        unsigned int* dst = (unsigned int*)(w2f + f * 512 + l * 8);
        dst[0] = pack2(a[0], a[1]); dst[1] = pack2(a[2], a[3]);
        dst[2] = pack2(b4[0], b4[1]); dst[3] = pack2(b4[2], b4[3]);
    }
}

__global__ __launch_bounds__(256) void gpath_kernel(
    const float* __restrict__ gw1, const float* __restrict__ gb1,
    const float* __restrict__ gg1, const float* __restrict__ gbe1,
    const float* __restrict__ gm1, const float* __restrict__ gv1,
    const float* __restrict__ gw2, const float* __restrict__ gb2,
    const float* __restrict__ gg2, const float* __restrict__ gbe2,
    const float* __restrict__ gm2, const float* __restrict__ gv2,
    float* __restrict__ wsf)
{
    __shared__ float xbar[192], hbuf[96];
    const int b = blockIdx.x, t = threadIdx.x;
    if (t < 192) xbar[t] = wsf[b * 192 + t];
    __syncthreads();
    if (t < 96) {
        float acc = 0.f;
        #pragma unroll 8
        for (int c = 0; c < 192; ++c) acc += gw1[t * 192 + c] * xbar[c];
        float s = gg1[t] * __frsqrt_rn(gv1[t] + 1e-5f);
        float tt = (gb1[t] - gm1[t]) * s + gbe1[t];
        hbuf[t] = fmaxf(acc * s + tt, 0.f);
    }
    __syncthreads();
    if (t < 192) {
        float acc = 0.f;
        #pragma unroll 8
        for (int j = 0; j < 96; ++j) acc += gw2[t * 96 + j] * hbuf[j];
        float s = gg2[t] * __frsqrt_rn(gv2[t] + 1e-5f);
        float tt = (gb2[t] - gm2[t]) * s + gbe2[t];
        wsf[1536 + b * 192 + t] = acc * s + tt;
    }
}

// 64-pixel tiles, 2048 blocks. LDS = lx only (25600 B) -> 6 blocks/CU.
// ZERO barriers: every wave touches only its own 16-row quarter of lx (staging,
// a-frags, lh) and all parameters live in registers loaded straight from wsf.
// sched_barrier(0) fences pin the load batching / weight ping-pong the compiler
// undid in round 3 (VGPR=52 evidence).
__global__ __launch_bounds__(256, 6) void main_kernel(
    const float* __restrict__ x1, const float* __restrict__ x2, const float* __restrict__ x3,
    const float* __restrict__ wsf,
    const unsigned short* __restrict__ w1f, const unsigned short* __restrict__ w2f,
    float* __restrict__ out)
{
    __shared__ __align__(16) unsigned short lx[64 * XSTR];   // wave-private quarters

    const int t = threadIdx.x;
    const int b = blockIdx.x >> 8;
    const int pix0 = (blockIdx.x & 255) << 6;
    const int lane = t & 63;
    const int wv = t >> 6;
    const int col = lane & 15;
    const int q = lane >> 4;
    const int pixw = wv * 16;
    const int pq = t >> 4;        // pixel quad 0..15 (wave w owns 4w..4w+3)
    const int cb = t & 15;

    const unsigned short* wb1 = w1f + lane * 8;
    const unsigned short* wb2 = w2f + lane * 8;

#define LD6(W, BASE, SET)                                                   \
    _Pragma("unroll")                                                       \
    for (int i_ = 0; i_ < 6; ++i_)                                          \
        W[i_] = *(const s16x8*)((BASE) + ((SET) * 6 + i_) * 512);
#define MF6_1(AK, W)                                                        \
    _Pragma("unroll")                                                       \
    for (int n_ = 0; n_ < 6; ++n_)                                          \
        acc1[n_] = __builtin_amdgcn_mfma_f32_16x16x32_bf16(AK, W[n_], acc1[n_], 0, 0, 0);
#define MF6_2(AK, W, NBO)                                                   \
    _Pragma("unroll")                                                       \
    for (int n_ = 0; n_ < 6; ++n_)                                          \
        acc2[(NBO) + n_] = __builtin_amdgcn_mfma_f32_16x16x32_bf16(AK, W[n_], acc2[(NBO) + n_], 0, 0, 0);

    // ---- issue ALL 12 staging HBM loads + W1 set0, as one batch ----
    f32x4 va[6], vb[6];
    #pragma unroll
    for (int i = 0; i < 6; ++i) {
        int cp = i * 16 + cb, c0 = cp * 2;
        int g = c0 >> 6, cc0 = c0 & 63;
        const float* pl = (g == 0 ? x1 : (g == 1 ? x2 : x3))
            + ((size_t)(b * 64 + cc0)) * HWPIX + pix0 + pq * 4;
        va[i] = *(const f32x4*)pl;
        vb[i] = *(const f32x4*)(pl + HWPIX);
    }
    s16x8 wA[6], wB[6];
    LD6(wA, wb1, 0);
    SBAR();

    // ---- convert + write own quarter (bf16 [pix][ch], pair-packed words) ----
    {
        unsigned int* lx32 = (unsigned int*)lx;
        #pragma unroll
        for (int i = 0; i < 6; ++i) {
            int cp = i * 16 + cb;
            #pragma unroll
            for (int j = 0; j < 4; ++j)
                lx32[(pq * 4 + j) * 100 + cp] = cvtpk(va[i][j], vb[i][j]);
        }
    }

    // a-frag preload (own rows only; same-wave DS ordering guarantees visibility)
    s16x8 a1[6];
    #pragma unroll
    for (int kb = 0; kb < 6; ++kb)
        a1[kb] = *(const s16x8*)&lx[(pixw + col) * XSTR + kb * 32 + q * 8];

    // W1 set1, then raw params (issued early, consumed much later; L2 hits)
    LD6(wB, wb1, 1);
    float s1v[6], t1v[6];
    #pragma unroll
    for (int nb = 0; nb < 6; ++nb) {
        int j = nb * 16 + col;
        s1v[nb] = wsf[3072 + j]; t1v[nb] = wsf[3168 + j];
    }
    float s2v[12], t2v[12], xgv[12];
    #pragma unroll
    for (int i = 0; i < 12; ++i) {
        int c = i * 16 + col;
        s2v[i] = wsf[3264 + c]; t2v[i] = wsf[3456 + c]; xgv[i] = wsf[1536 + b * 192 + c];
    }
    SBAR();

    // ---- Phase 1: H = relu(bn1(X @ W1^T)), 6-step weight ping-pong ----
    f32x4 acc1[6];
    #pragma unroll
    for (int nb = 0; nb < 6; ++nb) acc1[nb] = (f32x4){0.f, 0.f, 0.f, 0.f};

    MF6_1(a1[0], wA);
    LD6(wA, wb1, 2); SBAR(); MF6_1(a1[1], wB);
    LD6(wB, wb1, 3); SBAR(); MF6_1(a1[2], wA);
    LD6(wA, wb1, 4); SBAR(); MF6_1(a1[3], wB);
    LD6(wB, wb1, 5); SBAR(); MF6_1(a1[4], wA);
    LD6(wA, wb2, 0); SBAR(); MF6_1(a1[5], wB);   // also prefetch W2 set0

    // ---- lh write into own quarter ----
    unsigned short* lhp = &lx[pixw * XSTR];
    #pragma unroll
    for (int nbp = 0; nbp < 3; ++nbp) {
        int j0 = (2 * nbp) * 16 + col, j1 = (2 * nbp + 1) * 16 + col;
        #pragma unroll
        for (int r = 0; r < 4; ++r) {
            float h0 = fmaxf(acc1[2 * nbp][r]     * s1v[2 * nbp]     + t1v[2 * nbp], 0.f);
            float h1 = fmaxf(acc1[2 * nbp + 1][r] * s1v[2 * nbp + 1] + t1v[2 * nbp + 1], 0.f);
            unsigned int w = cvtpk(h0, h1);
            int rowo = (q * 4 + r) * HSTR;
            lhp[rowo + j0] = (unsigned short)w;
            lhp[rowo + j1] = (unsigned short)(w >> 16);
        }
    }

    // a2 preload + W2 set1 + epilogue x loads (all issued before phase-2 MFMAs)
    s16x8 a2[3];
    #pragma unroll
    for (int kb = 0; kb < 3; ++kb)
        a2[kb] = *(const s16x8*)&lhp[col * HSTR + kb * 32 + q * 8];
    LD6(wB, wb2, 1);
    f32x4 xa[4], xb4[4], xc4[4];
    size_t po[4];
    #pragma unroll
    for (int nb = 0; nb < 4; ++nb) {
        int cc = nb * 16 + col;
        po[nb] = ((size_t)(b * 64 + cc)) * HWPIX + pix0 + pixw + q * 4;
        xa[nb]  = *(const f32x4*)(x1 + po[nb]);
        xb4[nb] = *(const f32x4*)(x2 + po[nb]);
        xc4[nb] = *(const f32x4*)(x3 + po[nb]);
    }
    SBAR();

    // ---- Phase 2: XL = bn2(H @ W2^T), 6 half-steps, ping-pong ----
    f32x4 acc2[12];
    #pragma unroll
    for (int nb = 0; nb < 12; ++nb) acc2[nb] = (f32x4){0.f, 0.f, 0.f, 0.f};

    MF6_2(a2[0], wA, 0);
    LD6(wA, wb2, 2); SBAR(); MF6_2(a2[0], wB, 6);
    LD6(wB, wb2, 3); SBAR(); MF6_2(a2[1], wA, 0);
    LD6(wA, wb2, 4); SBAR(); MF6_2(a2[1], wB, 6);
    LD6(wB, wb2, 5); SBAR(); MF6_2(a2[2], wA, 0);
    SBAR();          MF6_2(a2[2], wB, 6);

    // ---- Epilogue: fold params, sigmoid via exp2+rcp, softmax w/o max-sub ----
    float Ap[12], Bp[12];
    #pragma unroll
    for (int i = 0; i < 12; ++i) {
        Ap[i] = -L2E * s2v[i];
        Bp[i] = -L2E * (t2v[i] + xgv[i]);
    }
    #pragma unroll
    for (int nb = 0; nb < 4; ++nb) {
        f32x4 res;
        #pragma unroll
        for (int r = 0; r < 4; ++r) {
            float w0 = __builtin_amdgcn_rcpf(1.f + __builtin_amdgcn_exp2f(acc2[nb][r]     * Ap[nb]     + Bp[nb]));
            float w1 = __builtin_amdgcn_rcpf(1.f + __builtin_amdgcn_exp2f(acc2[nb + 4][r] * Ap[nb + 4] + Bp[nb + 4]));
            float w2 = __builtin_amdgcn_rcpf(1.f + __builtin_amdgcn_exp2f(acc2[nb + 8][r] * Ap[nb + 8] + Bp[nb + 8]));
            float e0 = __builtin_amdgcn_exp2f(w0 * L2E);
            float e1 = __builtin_amdgcn_exp2f(w1 * L2E);
            float e2 = __builtin_amdgcn_exp2f(w2 * L2E);
            float inv = __builtin_amdgcn_rcpf(e0 + e1 + e2);
            res[r] = (e0 * xa[nb][r] + e1 * xb4[nb][r] + e2 * xc4[nb][r]) * inv;
        }
        *(f32x4*)(out + po[nb]) = res;
    }
#undef LD6
#undef MF6_1
#undef MF6_2
}

extern "C" void kernel_launch(void* const* d_in, const int* in_sizes, int n_in,
                              void* d_out, int out_size, void* d_ws, size_t ws_size,
                              hipStream_t stream) {
    (void)in_sizes; (void)n_in; (void)out_size; (void)ws_size;
    const float* x1  = (const float*)d_in[0];
    const float* x2  = (const float*)d_in[1];
    const float* x3  = (const float*)d_in[2];
    const float* lw1 = (const float*)d_in[3];
    const float* lb1 = (const float*)d_in[4];
    const float* lg1 = (const float*)d_in[5];
    const float* lbe1= (const float*)d_in[6];
    const float* lm1 = (const float*)d_in[7];
    const float* lv1 = (const float*)d_in[8];
    const float* lw2 = (const float*)d_in[9];
    const float* lb2 = (const float*)d_in[10];
    const float* lg2 = (const float*)d_in[11];
    const float* lbe2= (const float*)d_in[12];
    const float* lm2 = (const float*)d_in[13];
    const float* lv2 = (const float*)d_in[14];
    const float* gw1 = (const float*)d_in[15];
    const float* gb1 = (const float*)d_in[16];
    const float* gg1 = (const float*)d_in[17];
    const float* gbe1= (const float*)d_in[18];
    const float* gm1 = (const float*)d_in[19];
    const float* gv1 = (const float*)d_in[20];
    const float* gw2 = (const float*)d_in[21];
    const float* gb2 = (const float*)d_in[22];
    const float* gg2 = (const float*)d_in[23];
    const float* gbe2= (const float*)d_in[24];
    const float* gm2 = (const float*)d_in[25];
    const float* gv2 = (const float*)d_in[26];

    float* wsf = (float*)d_ws;
    unsigned short* w1f = (unsigned short*)((char*)d_ws + 16384);
    unsigned short* w2f = w1f + 18432;   // 36864 bytes after w1f

    prep_kernel<<<1556, 256, 0, stream>>>(x1, x2, x3,
        lw1, lb1, lg1, lbe1, lm1, lv1, lw2, lb2, lg2, lbe2, lm2, lv2,
        wsf, w1f, w2f);
    gpath_kernel<<<8, 256, 0, stream>>>(
        gw1, gb1, gg1, gbe1, gm1, gv1, gw2, gb2, gg2, gbe2, gm2, gv2, wsf);
    main_kernel<<<2048, 256, 0, stream>>>(x1, x2, x3, wsf, w1f, w2f, (float*)d_out);
}

// Round 7
// 236.302 us; speedup vs baseline: 1.9991x; 1.9991x over previous
//
#include <hip/hip_runtime.h>

#define HWPIX 16384
#define XSTR 200   // lx stride in shorts (100 words); per-wave quarter also hosts lh
#define HSTR 104   // lh stride in shorts (52 words)
#define L2E 1.4426950408889634f

typedef float f32x4 __attribute__((ext_vector_type(4)));
typedef short s16x8 __attribute__((ext_vector_type(8)));

static __device__ __forceinline__ unsigned short f2bf(float f) {
    unsigned int u = __builtin_bit_cast(unsigned int, f);
    u += 0x7fffu + ((u >> 16) & 1u);
    return (unsigned short)(u >> 16);
}
static __device__ __forceinline__ unsigned int pack2(float lo, float hi) {
    return (unsigned int)f2bf(lo) | ((unsigned int)f2bf(hi) << 16);
}
// HW packed f32->bf16 (RNE), one instruction for two converts
static __device__ __forceinline__ unsigned int cvtpk(float lo, float hi) {
    unsigned int r;
    asm("v_cvt_pk_bf16_f32 %0, %1, %2" : "=v"(r) : "v"(lo), "v"(hi));
    return r;
}

#define SBAR() __builtin_amdgcn_sched_barrier(0)

// ws layout: floats [0,1536) gmean, [1536,3072) xg, [3072,3168) s1l, [3168,3264) t1l,
// [3264,3456) s2l, [3456,3648) t2l. Byte 16384: W1 bf16 frags (36864 B), then W2 frags.

__global__ __launch_bounds__(256) void prep_kernel(
    const float* __restrict__ x1, const float* __restrict__ x2, const float* __restrict__ x3,
    const float* __restrict__ lw1, const float* __restrict__ lb1,
    const float* __restrict__ lg1, const float* __restrict__ lbe1,
    const float* __restrict__ lm1, const float* __restrict__ lv1,
    const float* __restrict__ lw2, const float* __restrict__ lb2,
    const float* __restrict__ lg2, const float* __restrict__ lbe2,
    const float* __restrict__ lm2, const float* __restrict__ lv2,
    float* __restrict__ wsf, unsigned short* __restrict__ w1f, unsigned short* __restrict__ w2f)
{
    const int bid = blockIdx.x, t = threadIdx.x;
    if (bid < 1536) {
        // GAP over one (b, channel) fp32 plane: 16384 floats
        int b = bid / 192, c = bid % 192;
        int g = c >> 6, cc = c & 63;
        const float* base = (g == 0 ? x1 : (g == 1 ? x2 : x3)) + ((size_t)(b * 64 + cc)) * HWPIX;
        float s = 0.f;
        #pragma unroll
        for (int it = 0; it < 16; ++it) {
            f32x4 v = *(const f32x4*)(base + it * 1024 + t * 4);
            s += v[0] + v[1] + v[2] + v[3];
        }
        for (int off = 32; off > 0; off >>= 1) s += __shfl_down(s, off, 64);
        __shared__ float part[4];
        if ((t & 63) == 0) part[t >> 6] = s;
        __syncthreads();
        if (t == 0) wsf[bid] = (part[0] + part[1] + part[2] + part[3]) * (1.f / (float)HWPIX);
    } else if (bid == 1536) {
        if (t < 96) {
            float s = lg1[t] * __frsqrt_rn(lv1[t] + 1e-5f);
            wsf[3072 + t] = s;
            wsf[3168 + t] = (lb1[t] - lm1[t]) * s + lbe1[t];
        }
    } else if (bid == 1537) {
        if (t < 192) {
            float s = lg2[t] * __frsqrt_rn(lv2[t] + 1e-5f);
            wsf[3264 + t] = s;
            wsf[3456 + t] = (lb2[t] - lm2[t]) * s + lbe2[t];
        }
    } else if (bid < 1547) {
        // W1 pretile fp32 -> bf16 B-frags. frag f = kb*6+nb; lane l holds
        // B[k=(l>>4)*8+j][n=l&15] with B=W1^T -> W1[row=n][col=k..k+7]
        int slot = (bid - 1538) * 256 + t;          // [0, 2304)
        int f = slot >> 6, l = slot & 63;
        int kb = f / 6, nb = f % 6;
        int row = nb * 16 + (l & 15), col0 = kb * 32 + ((l >> 4) << 3);
        const float* src = lw1 + row * 192 + col0;
        f32x4 a = *(const f32x4*)src, b4 = *(const f32x4*)(src + 4);
        unsigned int* dst = (unsigned int*)(w1f + f * 512 + l * 8);
        dst[0] = pack2(a[0], a[1]); dst[1] = pack2(a[2], a[3]);
        dst[2] = pack2(b4[0], b4[1]); dst[3] = pack2(b4[2], b4[3]);
    } else {
        // W2 pretile: frag f = kb*12+nb; W2[row=n][col=k..k+7], rows 0..191, cols 0..95
        int slot = (bid - 1547) * 256 + t;
        int f = slot >> 6, l = slot & 63;
        int kb = f / 12, nb = f % 12;
        int row = nb * 16 + (l & 15), col0 = kb * 32 + ((l >> 4) << 3);
        const float* src = lw2 + row * 96 + col0;
        f32x4 a = *(const f32x4*)src, b4 = *(const f32x4*)(src + 4);
        unsigned int* dst = (unsigned int*)(w2f + f * 512 + l * 8);
        dst[0] = pack2(a[0], a[1]); dst[1] = pack2(a[2], a[3]);
        dst[2] = pack2(b4[0], b4[1]); dst[3] = pack2(b4[2], b4[3]);
    }
}

__global__ __launch_bounds__(256) void gpath_kernel(
    const float* __restrict__ gw1, const float* __restrict__ gb1,
    const float* __restrict__ gg1, const float* __restrict__ gbe1,
    const float* __restrict__ gm1, const float* __restrict__ gv1,
    const float* __restrict__ gw2, const float* __restrict__ gb2,
    const float* __restrict__ gg2, const float* __restrict__ gbe2,
    const float* __restrict__ gm2, const float* __restrict__ gv2,
    float* __restrict__ wsf)
{
    __shared__ float xbar[192], hbuf[96];
    const int b = blockIdx.x, t = threadIdx.x;
    if (t < 192) xbar[t] = wsf[b * 192 + t];
    __syncthreads();
    if (t < 96) {
        float acc = 0.f;
        #pragma unroll 8
        for (int c = 0; c < 192; ++c) acc += gw1[t * 192 + c] * xbar[c];
        float s = gg1[t] * __frsqrt_rn(gv1[t] + 1e-5f);
        float tt = (gb1[t] - gm1[t]) * s + gbe1[t];
        hbuf[t] = fmaxf(acc * s + tt, 0.f);
    }
    __syncthreads();
    if (t < 192) {
        float acc = 0.f;
        #pragma unroll 8
        for (int j = 0; j < 96; ++j) acc += gw2[t * 96 + j] * hbuf[j];
        float s = gg2[t] * __frsqrt_rn(gv2[t] + 1e-5f);
        float tt = (gb2[t] - gm2[t]) * s + gbe2[t];
        wsf[1536 + b * 192 + t] = acc * s + tt;
    }
}

// 64-pixel tiles, 2048 blocks. LDS = lx only (25600 B). ZERO barriers (wave-private
// lx quarters). __launch_bounds__(256,4) -> 128-VGPR cap: pipeline sized to ~120 live
// (a-frags 2-ahead, epilogue params/x-loads deferred past phase 2, two-half epilogue).
__global__ __launch_bounds__(256, 4) void main_kernel(
    const float* __restrict__ x1, const float* __restrict__ x2, const float* __restrict__ x3,
    const float* __restrict__ wsf,
    const unsigned short* __restrict__ w1f, const unsigned short* __restrict__ w2f,
    float* __restrict__ out)
{
    __shared__ __align__(16) unsigned short lx[64 * XSTR];   // wave-private quarters

    const int t = threadIdx.x;
    const int b = blockIdx.x >> 8;
    const int pix0 = (blockIdx.x & 255) << 6;
    const int lane = t & 63;
    const int wv = t >> 6;
    const int col = lane & 15;
    const int q = lane >> 4;
    const int pixw = wv * 16;
    const int pq = t >> 4;        // pixel quad 0..15 (wave w owns 4w..4w+3)
    const int cb = t & 15;

    const unsigned short* wb1 = w1f + lane * 8;
    const unsigned short* wb2 = w2f + lane * 8;

#define LD6(W, BASE, SET)                                                   \
    _Pragma("unroll")                                                       \
    for (int i_ = 0; i_ < 6; ++i_)                                          \
        W[i_] = *(const s16x8*)((BASE) + ((SET) * 6 + i_) * 512);
#define LDA1(K) (*(const s16x8*)&lx[(pixw + col) * XSTR + (K) * 32 + q * 8])
#define MF6_1(AK, W)                                                        \
    _Pragma("unroll")                                                       \
    for (int n_ = 0; n_ < 6; ++n_)                                          \
        acc1[n_] = __builtin_amdgcn_mfma_f32_16x16x32_bf16(AK, W[n_], acc1[n_], 0, 0, 0);
#define MF6_2(AK, W, NBO)                                                   \
    _Pragma("unroll")                                                       \
    for (int n_ = 0; n_ < 6; ++n_)                                          \
        acc2[(NBO) + n_] = __builtin_amdgcn_mfma_f32_16x16x32_bf16(AK, W[n_], acc2[(NBO) + n_], 0, 0, 0);

    // ---- issue ALL 12 staging HBM loads + W1 set0 + bn1 params, as one batch ----
    f32x4 va[6], vb[6];
    #pragma unroll
    for (int i = 0; i < 6; ++i) {
        int cp = i * 16 + cb, c0 = cp * 2;
        int g = c0 >> 6, cc0 = c0 & 63;
        const float* pl = (g == 0 ? x1 : (g == 1 ? x2 : x3))
            + ((size_t)(b * 64 + cc0)) * HWPIX + pix0 + pq * 4;
        va[i] = *(const f32x4*)pl;
        vb[i] = *(const f32x4*)(pl + HWPIX);
    }
    s16x8 wA[6], wB[6];
    LD6(wA, wb1, 0);
    float s1v[6], t1v[6];
    #pragma unroll
    for (int nb = 0; nb < 6; ++nb) {
        int j = nb * 16 + col;
        s1v[nb] = wsf[3072 + j]; t1v[nb] = wsf[3168 + j];
    }
    SBAR();

    // ---- convert + write own quarter (bf16 [pix][ch], pair-packed words) ----
    {
        unsigned int* lx32 = (unsigned int*)lx;
        #pragma unroll
        for (int i = 0; i < 6; ++i) {
            int cp = i * 16 + cb;
            #pragma unroll
            for (int j = 0; j < 4; ++j)
                lx32[(pq * 4 + j) * 100 + cp] = cvtpk(va[i][j], vb[i][j]);
        }
    }
    LD6(wB, wb1, 1);
    s16x8 aa = LDA1(0), ab = LDA1(1);   // a-frags 2-ahead (own rows; in-order DS pipe)
    SBAR();

    // ---- Phase 1: H = relu(bn1(X @ W1^T)), 6-step weight ping-pong ----
    f32x4 acc1[6];
    #pragma unroll
    for (int nb = 0; nb < 6; ++nb) acc1[nb] = (f32x4){0.f, 0.f, 0.f, 0.f};

    MF6_1(aa, wA); LD6(wA, wb1, 2); aa = LDA1(2); SBAR();
    MF6_1(ab, wB); LD6(wB, wb1, 3); ab = LDA1(3); SBAR();
    MF6_1(aa, wA); LD6(wA, wb1, 4); aa = LDA1(4); SBAR();
    MF6_1(ab, wB); LD6(wB, wb1, 5); ab = LDA1(5); SBAR();
    MF6_1(aa, wA); LD6(wA, wb2, 0); SBAR();       // prefetch W2 set0 into wA
    MF6_1(ab, wB);

    // ---- lh write into own quarter (covers W2-set0 latency) ----
    unsigned short* lhp = &lx[pixw * XSTR];
    #pragma unroll
    for (int nbp = 0; nbp < 3; ++nbp) {
        int j0 = (2 * nbp) * 16 + col, j1 = (2 * nbp + 1) * 16 + col;
        #pragma unroll
        for (int r = 0; r < 4; ++r) {
            float h0 = fmaxf(acc1[2 * nbp][r]     * s1v[2 * nbp]     + t1v[2 * nbp], 0.f);
            float h1 = fmaxf(acc1[2 * nbp + 1][r] * s1v[2 * nbp + 1] + t1v[2 * nbp + 1], 0.f);
            unsigned int w = cvtpk(h0, h1);
            int rowo = (q * 4 + r) * HSTR;
            lhp[rowo + j0] = (unsigned short)w;
            lhp[rowo + j1] = (unsigned short)(w >> 16);
        }
    }

    s16x8 a2[3];
    #pragma unroll
    for (int kb = 0; kb < 3; ++kb)
        a2[kb] = *(const s16x8*)&lhp[col * HSTR + kb * 32 + q * 8];
    LD6(wB, wb2, 1);
    SBAR();

    // ---- Phase 2: XL = bn2(H @ W2^T), 6 half-steps, ping-pong ----
    f32x4 acc2[12];
    #pragma unroll
    for (int nb = 0; nb < 12; ++nb) acc2[nb] = (f32x4){0.f, 0.f, 0.f, 0.f};

    MF6_2(a2[0], wA, 0); LD6(wA, wb2, 2); SBAR();
    MF6_2(a2[0], wB, 6); LD6(wB, wb2, 3); SBAR();
    MF6_2(a2[1], wA, 0); LD6(wA, wb2, 4); SBAR();
    MF6_2(a2[1], wB, 6); LD6(wB, wb2, 5); SBAR();
    MF6_2(a2[2], wA, 0); SBAR();
    MF6_2(a2[2], wB, 6);

    // ---- Epilogue (deferred loads; two halves to cap VGPR pressure) ----
    float Ap[12], Bp[12];
    #pragma unroll
    for (int i = 0; i < 12; ++i) {
        int c = i * 16 + col;
        float s2 = wsf[3264 + c], t2 = wsf[3456 + c], xg = wsf[1536 + b * 192 + c];
        Ap[i] = -L2E * s2;
        Bp[i] = -L2E * (t2 + xg);
    }
    #pragma unroll
    for (int h = 0; h < 2; ++h) {
        f32x4 xa[2], xbv[2], xcv[2];
        size_t po[2];
        #pragma unroll
        for (int k = 0; k < 2; ++k) {
            int nb = 2 * h + k, cc = nb * 16 + col;
            po[k] = ((size_t)(b * 64 + cc)) * HWPIX + pix0 + pixw + q * 4;
            xa[k]  = *(const f32x4*)(x1 + po[k]);
            xbv[k] = *(const f32x4*)(x2 + po[k]);
            xcv[k] = *(const f32x4*)(x3 + po[k]);
        }
        SBAR();
        #pragma unroll
        for (int k = 0; k < 2; ++k) {
            int nb = 2 * h + k;
            f32x4 res;
            #pragma unroll
            for (int r = 0; r < 4; ++r) {
                float w0 = __builtin_amdgcn_rcpf(1.f + __builtin_amdgcn_exp2f(acc2[nb][r]     * Ap[nb]     + Bp[nb]));
                float w1 = __builtin_amdgcn_rcpf(1.f + __builtin_amdgcn_exp2f(acc2[nb + 4][r] * Ap[nb + 4] + Bp[nb + 4]));
                float w2 = __builtin_amdgcn_rcpf(1.f + __builtin_amdgcn_exp2f(acc2[nb + 8][r] * Ap[nb + 8] + Bp[nb + 8]));
                float e0 = __builtin_amdgcn_exp2f(w0 * L2E);
                float e1 = __builtin_amdgcn_exp2f(w1 * L2E);
                float e2 = __builtin_amdgcn_exp2f(w2 * L2E);
                float inv = __builtin_amdgcn_rcpf(e0 + e1 + e2);
                res[r] = (e0 * xa[k][r] + e1 * xbv[k][r] + e2 * xcv[k][r]) * inv;
            }
            *(f32x4*)(out + po[k]) = res;
        }
    }
#undef LD6
#undef LDA1
#undef MF6_1
#undef MF6_2
}

extern "C" void kernel_launch(void* const* d_in, const int* in_sizes, int n_in,
                              void* d_out, int out_size, void* d_ws, size_t ws_size,
                              hipStream_t stream) {
    (void)in_sizes; (void)n_in; (void)out_size; (void)ws_size;
    const float* x1  = (const float*)d_in[0];
    const float* x2  = (const float*)d_in[1];
    const float* x3  = (const float*)d_in[2];
    const float* lw1 = (const float*)d_in[3];
    const float* lb1 = (const float*)d_in[4];
    const float* lg1 = (const float*)d_in[5];
    const float* lbe1= (const float*)d_in[6];
    const float* lm1 = (const float*)d_in[7];
    const float* lv1 = (const float*)d_in[8];
    const float* lw2 = (const float*)d_in[9];
    const float* lb2 = (const float*)d_in[10];
    const float* lg2 = (const float*)d_in[11];
    const float* lbe2= (const float*)d_in[12];
    const float* lm2 = (const float*)d_in[13];
    const float* lv2 = (const float*)d_in[14];
    const float* gw1 = (const float*)d_in[15];
    const float* gb1 = (const float*)d_in[16];
    const float* gg1 = (const float*)d_in[17];
    const float* gbe1= (const float*)d_in[18];
    const float* gm1 = (const float*)d_in[19];
    const float* gv1 = (const float*)d_in[20];
    const float* gw2 = (const float*)d_in[21];
    const float* gb2 = (const float*)d_in[22];
    const float* gg2 = (const float*)d_in[23];
    const float* gbe2= (const float*)d_in[24];
    const float* gm2 = (const float*)d_in[25];
    const float* gv2 = (const float*)d_in[26];

    float* wsf = (float*)d_ws;
    unsigned short* w1f = (unsigned short*)((char*)d_ws + 16384);
    unsigned short* w2f = w1f + 18432;   // 36864 bytes after w1f

    prep_kernel<<<1556, 256, 0, stream>>>(x1, x2, x3,
        lw1, lb1, lg1, lbe1, lm1, lv1, lw2, lb2, lg2, lbe2, lm2, lv2,
        wsf, w1f, w2f);
    gpath_kernel<<<8, 256, 0, stream>>>(
        gw1, gb1, gg1, gbe1, gm1, gv1, gw2, gb2, gg2, gbe2, gm2, gv2, wsf);
    main_kernel<<<2048, 256, 0, stream>>>(x1, x2, x3, wsf, w1f, w2f, (float*)d_out);
}